// Round 3
// baseline (380.226 us; speedup 1.0000x reference)
//
#include <hip/hip_runtime.h>

typedef __attribute__((ext_vector_type(8))) short short8;
typedef __attribute__((ext_vector_type(4))) float f32x4;
typedef __attribute__((ext_vector_type(4))) unsigned short u16x4;

#define GLOAD16(g, l)                                                          \
  __builtin_amdgcn_global_load_lds(                                            \
      (const __attribute__((address_space(1))) unsigned int*)(g),              \
      (__attribute__((address_space(3))) unsigned int*)(l), 16, 0, 0)

__device__ __forceinline__ unsigned short f2bf(float f) {
  unsigned int u = __float_as_uint(f);
  u += 0x7FFFu + ((u >> 16) & 1u);   // RNE
  return (unsigned short)(u >> 16);
}
__device__ __forceinline__ float bf2f(unsigned short h) {
  return __uint_as_float(((unsigned int)h) << 16);
}

// ---------------------------------------------------------------- mix / bmix
__global__ void mix_kernel(const float* __restrict__ amp,
                           const float* __restrict__ phase,
                           const float* __restrict__ bias,
                           float* __restrict__ mix, float* __restrict__ bmix) {
  int q = blockIdx.x * blockDim.x + threadIdx.x;  // 0..1023
  float a[16];
  float mx = -1e30f;
  for (int s = 0; s < 16; ++s) {
    a[s] = amp[s * 1024 + q];
    mx = fmaxf(mx, a[s]);
  }
  float sum = 0.f;
  for (int s = 0; s < 16; ++s) {
    a[s] = __expf(a[s] - mx);
    sum += a[s];
  }
  float inv = 1.f / sum;
  for (int s = 0; s < 16; ++s) {
    float m = a[s] * inv * cosf(phase[s * 1024 + q]);
    mix[s * 1024 + q] = m;
    bmix[s * 1024 + q] = bias[s * 1024 + q] * m;
  }
}

// ---------------------------------------------------------------- cast x->bf16
__global__ void cast_x_kernel(const float* __restrict__ x,
                              unsigned short* __restrict__ xb) {
  int i = (blockIdx.x * blockDim.x + threadIdx.x) * 4;
  float4 v = *(const float4*)(x + i);
  union { unsigned short h[4]; uint2 u; } o;
  o.h[0] = f2bf(v.x); o.h[1] = f2bf(v.y); o.h[2] = f2bf(v.z); o.h[3] = f2bf(v.w);
  *(uint2*)(xb + i) = o.u;
}

// ------------------------------------------------- transpose+cast W -> Wt bf16
// 64x64 tile through LDS: coalesced 256B row reads, 128B-contiguous writes.
__global__ __launch_bounds__(256) void transpose_w_kernel(
    const float* __restrict__ W, unsigned short* __restrict__ Wt) {
  __shared__ unsigned short tile[64][66];   // +2 pad: 4-way max on gather
  const int s = blockIdx.z;
  const int q0 = blockIdx.x * 64, i0 = blockIdx.y * 64;
  const int t = threadIdx.x;
  const float* Ws = W + (size_t)s * 1048576;
  unsigned short* Wts = Wt + (size_t)s * 1048576;
  const int rq = t & 63, ri = t >> 6;
  #pragma unroll
  for (int p = 0; p < 16; ++p)
    tile[p * 4 + ri][rq] = f2bf(Ws[(size_t)(i0 + p * 4 + ri) * 1024 + q0 + rq]);
  __syncthreads();
  const int wq = t >> 3, wi = (t & 7) * 8;
  #pragma unroll
  for (int o = 0; o < 2; ++o) {
    union { unsigned short h[8]; short8 v; } u;
    #pragma unroll
    for (int e = 0; e < 8; ++e) u.h[e] = tile[wi + e][o * 32 + wq];
    *(short8*)(Wts + (size_t)(q0 + o * 32 + wq) * 1024 + i0 + wi) = u.v;
  }
}

// ---------------------------------------------------------------- bf16 GEMM
// 256x256 tile, BK=64, 8 waves (2Mx4N), 8-phase schedule (T2+T3+T4+T5).
// LDS: A/B each 4 planes [bank(2)][half(2)] of 128rows x 64k bf16 (16KB).
// Swizzle: LDS(row,k') holds global k = k' ^ ((row&1)*32)  (bank-balanced
// b128 reads; applied via inverse-swizzled global source, linear LDS dst).
// Stage schedule (iter j, tiles t0=2j,t1=2j+1), derived so each stage is
// >=1 barrier after its slot's last read, vmcnt(4) at P4/P8 covers reads:
//  P1:A_h1(t1) P2:B_h1(t1) P3:B_h0(t0+2) P4:B_h1(t0+2)+vmcnt4
//  P5:A_h0(t0+2) P6:A_h1(t0+2) P7:B_h0(t1+2) P8:A_h0(t1+2)+vmcnt4
template <bool BF16SUP>
__global__ __launch_bounds__(512, 2) void gemm_kernel(
    const unsigned short* __restrict__ xb, const unsigned short* __restrict__ wt,
    const float* __restrict__ mix, const float* __restrict__ bmix,
    float* __restrict__ outf, unsigned short* __restrict__ sup) {
  __shared__ __align__(16) unsigned short As[4 * 8192];
  __shared__ __align__(16) unsigned short Bs[4 * 8192];

  const int tid = threadIdx.x;
  const int lane = tid & 63;
  const int wv = tid >> 6;
  const int wm = wv >> 2, wn = wv & 3;   // 2x4 waves, wave tile 128x64
  const int lr = lane & 15;
  const int g8 = (lane >> 4) * 8;
  const int par = (lr & 1) << 5;          // read-side swizzle term

  // XCD swizzle + L2 grouping: each XCD chunk covers all 16 M-tiles x 8 N-tiles
  const int id = blockIdx.x;
  const int swz = (id & 7) * 128 + (id >> 3);
  const int local = swz & 127;
  const int by = local & 15;
  const int bx = (swz >> 7) * 8 + (local >> 4);
  const int m0 = by * 256, n0 = bx * 256;

  // staging: thread covers row tid>>3 (+64 for 2nd load), 8 elems at
  // swizzled k: k8s = (tid&7)*8 ^ ((row&1)*32)
  const int srow = tid >> 3;
  const int k8s = ((tid & 7) * 8) ^ ((srow & 1) << 5);
  const int t8 = tid * 8;
  const unsigned short* gA = xb + (size_t)(m0 + srow) * 1024 + k8s;
  const unsigned short* gB = wt + (size_t)(n0 + srow) * 1024 + k8s;

#define STG(gbase, lds, tile, half) do {                                       \
    const unsigned short* _g = (gbase) + (half) * 131072 + (tile) * 64;        \
    unsigned short* _l = (lds) + ((((tile) & 1) * 2 + (half)) * 8192) + t8;    \
    GLOAD16(_g, _l);                                                           \
    GLOAD16(_g + 65536, _l + 4096);                                            \
  } while (0)

  short8 a[4][2], bl[2][2], bh[2][2];
  f32x4 acc[8][4];
  #pragma unroll
  for (int i = 0; i < 8; ++i)
    #pragma unroll
    for (int j = 0; j < 4; ++j) acc[i][j] = (f32x4){0.f, 0.f, 0.f, 0.f};

#define RD_A(bank, hib) do {                                                   \
    const unsigned short* _p = &As[((bank) * 2 + wm) * 8192] +                 \
                               ((hib) * 64 + lr) * 64 + g8;                    \
    _Pragma("unroll")                                                          \
    for (int mi = 0; mi < 4; ++mi) {                                           \
      a[mi][0] = *(const short8*)(_p + mi * 1024 + par);                       \
      a[mi][1] = *(const short8*)(_p + mi * 1024 + (32 ^ par));                \
    }                                                                          \
  } while (0)

#define RD_B(dst, bank, hib) do {                                              \
    const unsigned short* _p = &Bs[((bank) * 2 + (wn >> 1)) * 8192] +          \
                               ((wn & 1) * 64 + (hib) * 32 + lr) * 64 + g8;    \
    _Pragma("unroll")                                                          \
    for (int ni = 0; ni < 2; ++ni) {                                           \
      dst[ni][0] = *(const short8*)(_p + ni * 1024 + par);                     \
      dst[ni][1] = *(const short8*)(_p + ni * 1024 + (32 ^ par));              \
    }                                                                          \
  } while (0)

#define MMQ(M0, N0, BB)                                                        \
    _Pragma("unroll")                                                          \
    for (int mi = 0; mi < 4; ++mi)                                             \
      _Pragma("unroll")                                                        \
      for (int ni = 0; ni < 2; ++ni) {                                         \
        acc[(M0) + mi][(N0) + ni] = __builtin_amdgcn_mfma_f32_16x16x32_bf16(   \
            a[mi][0], BB[ni][0], acc[(M0) + mi][(N0) + ni], 0, 0, 0);          \
        acc[(M0) + mi][(N0) + ni] = __builtin_amdgcn_mfma_f32_16x16x32_bf16(   \
            a[mi][1], BB[ni][1], acc[(M0) + mi][(N0) + ni], 0, 0, 0);          \
      }

#define PH_SYNC()                                                              \
    __builtin_amdgcn_s_barrier();                                              \
    asm volatile("s_waitcnt lgkmcnt(0)" ::: "memory");                         \
    __builtin_amdgcn_sched_barrier(0);                                         \
    __builtin_amdgcn_s_setprio(1)

#define PH_END()                                                               \
    __builtin_amdgcn_s_setprio(0);                                             \
    __builtin_amdgcn_s_barrier()

  // prologue: tile0 all 4 halves + B_h0(1) + A_h0(1); keep last 2 in flight
  STG(gB, Bs, 0, 0); STG(gB, Bs, 0, 1);
  STG(gA, As, 0, 0); STG(gA, As, 0, 1);
  STG(gB, Bs, 1, 0); STG(gA, As, 1, 0);
  asm volatile("s_waitcnt vmcnt(4)" ::: "memory");
  __builtin_amdgcn_s_barrier();

  for (int j = 0; j < 8; ++j) {
    const int t1 = 2 * j + 1;
    // P1: Q00(t0)
    RD_A(0, 0); RD_B(bl, 0, 0);
    STG(gA, As, t1, 1);
    PH_SYNC(); MMQ(0, 0, bl); PH_END();
    // P2: Q01(t0)
    RD_B(bh, 0, 1);
    STG(gB, Bs, t1, 1);
    PH_SYNC(); MMQ(0, 2, bh); PH_END();
    // P3: Q11(t0)
    RD_A(0, 1);
    if (j < 7) STG(gB, Bs, t1 + 1, 0);
    PH_SYNC(); MMQ(4, 2, bh); PH_END();
    // P4: Q10(t0)
    if (j < 7) {
      STG(gB, Bs, t1 + 1, 1);
      asm volatile("s_waitcnt vmcnt(4)" ::: "memory");
    } else {
      asm volatile("s_waitcnt vmcnt(0)" ::: "memory");
    }
    PH_SYNC(); MMQ(4, 0, bl); PH_END();
    // P5: Q00(t1)
    RD_A(1, 0); RD_B(bl, 1, 0);
    if (j < 7) STG(gA, As, t1 + 1, 0);
    PH_SYNC(); MMQ(0, 0, bl); PH_END();
    // P6: Q01(t1)
    RD_B(bh, 1, 1);
    if (j < 7) STG(gA, As, t1 + 1, 1);
    PH_SYNC(); MMQ(0, 2, bh); PH_END();
    // P7: Q11(t1)
    RD_A(1, 1);
    if (j < 7) STG(gB, Bs, t1 + 2, 0);
    PH_SYNC(); MMQ(4, 2, bh); PH_END();
    // P8: Q10(t1)
    if (j < 7) {
      STG(gA, As, t1 + 2, 0);
      asm volatile("s_waitcnt vmcnt(4)" ::: "memory");
    }
    PH_SYNC(); MMQ(4, 0, bl); PH_END();
  }
#undef STG
#undef RD_A
#undef RD_B
#undef MMQ
#undef PH_SYNC
#undef PH_END

  // epilogue: sup = acc*mix + bmix
  #pragma unroll
  for (int ni = 0; ni < 4; ++ni) {
    const int n = n0 + wn * 64 + ni * 16 + lr;
    const float mv = mix[n];
    const float bvv = bmix[n];
    #pragma unroll
    for (int mi = 0; mi < 8; ++mi) {
      const int m = m0 + wm * 128 + mi * 16 + (lane >> 4) * 4;
      #pragma unroll
      for (int r = 0; r < 4; ++r) {
        float v = acc[mi][ni][r] * mv + bvv;
        if (BF16SUP)
          sup[(size_t)(m + r) * 16384 + n] = f2bf(v);
        else
          outf[(size_t)(m + r) * 16384 + n] = v;
      }
    }
  }
}

// ------------------------------------------------------- LN from bf16 sup
__global__ __launch_bounds__(256) void ln_bf16_kernel(
    const unsigned short* __restrict__ sup, float* __restrict__ out,
    const float* __restrict__ gamma, const float* __restrict__ beta) {
  __shared__ float red[8];
  const int t = threadIdx.x;
  const size_t base = (size_t)blockIdx.x * 1024;
  u16x4 raw = *(const u16x4*)(sup + base + t * 4);
  float v[4];
  #pragma unroll
  for (int j = 0; j < 4; ++j) v[j] = bf2f(raw[j]);
  float s = v[0] + v[1] + v[2] + v[3];
  float ss = v[0] * v[0] + v[1] * v[1] + v[2] * v[2] + v[3] * v[3];
  #pragma unroll
  for (int m = 32; m >= 1; m >>= 1) {
    s += __shfl_xor(s, m);
    ss += __shfl_xor(ss, m);
  }
  const int wv = t >> 6;
  if ((t & 63) == 0) { red[wv * 2] = s; red[wv * 2 + 1] = ss; }
  __syncthreads();
  const float S = red[0] + red[2] + red[4] + red[6];
  const float SS = red[1] + red[3] + red[5] + red[7];
  const float mean = S * (1.0f / 1024.0f);
  const float var = SS * (1.0f / 1024.0f) - mean * mean;
  const float rstd = rsqrtf(var + 1e-5f);
  const float4 g = *(const float4*)(gamma + t * 4);
  const float4 b = *(const float4*)(beta + t * 4);
  float4 o;
  o.x = (v[0] - mean) * rstd * g.x + b.x;
  o.y = (v[1] - mean) * rstd * g.y + b.y;
  o.z = (v[2] - mean) * rstd * g.z + b.z;
  o.w = (v[3] - mean) * rstd * g.w + b.w;
  *(float4*)(out + base + t * 4) = o;
}

// ------------------------------------------------------- in-place f32 LN
__global__ __launch_bounds__(256) void ln_kernel(float* __restrict__ out,
                                                 const float* __restrict__ gamma,
                                                 const float* __restrict__ beta) {
  __shared__ float red[8];
  const int t = threadIdx.x;
  const size_t base = (size_t)blockIdx.x * 1024;
  float4 v = *(const float4*)(out + base + t * 4);
  float s = v.x + v.y + v.z + v.w;
  float ss = v.x * v.x + v.y * v.y + v.z * v.z + v.w * v.w;
  #pragma unroll
  for (int m = 32; m >= 1; m >>= 1) {
    s += __shfl_xor(s, m);
    ss += __shfl_xor(ss, m);
  }
  const int wv = t >> 6;
  if ((t & 63) == 0) { red[wv * 2] = s; red[wv * 2 + 1] = ss; }
  __syncthreads();
  const float S = red[0] + red[2] + red[4] + red[6];
  const float SS = red[1] + red[3] + red[5] + red[7];
  const float mean = S * (1.0f / 1024.0f);
  const float var = SS * (1.0f / 1024.0f) - mean * mean;
  const float rstd = rsqrtf(var + 1e-5f);
  const float4 g = *(const float4*)(gamma + t * 4);
  const float4 b = *(const float4*)(beta + t * 4);
  float4 o;
  o.x = (v.x - mean) * rstd * g.x + b.x;
  o.y = (v.y - mean) * rstd * g.y + b.y;
  o.z = (v.z - mean) * rstd * g.z + b.z;
  o.w = (v.w - mean) * rstd * g.w + b.w;
  *(float4*)(out + base + t * 4) = o;
}

extern "C" void kernel_launch(void* const* d_in, const int* in_sizes, int n_in,
                              void* d_out, int out_size, void* d_ws, size_t ws_size,
                              hipStream_t stream) {
  (void)in_sizes; (void)n_in; (void)out_size;
  const float* x     = (const float*)d_in[0];  // [4096,1024]
  const float* W     = (const float*)d_in[1];  // [16,1024,1024]
  const float* bias  = (const float*)d_in[2];  // [16,1024]
  const float* amp   = (const float*)d_in[3];  // [16,1024]
  const float* phase = (const float*)d_in[4];  // [16,1024]
  const float* gamma = (const float*)d_in[5];  // [1024]
  const float* beta  = (const float*)d_in[6];  // [1024]
  float* out = (float*)d_out;                  // [4096,16,1024] = 256 MiB

  const bool big = ws_size >= (size_t)134217728ULL;  // bf16 sup fits in ws

  unsigned short *Wt, *xbuf, *supb = nullptr;
  float *mixp, *bmixp;
  if (big) {
    // scratch Wt/xb/mix live in d_out (fully rewritten by LN afterwards);
    // ws holds bf16 sup (exactly 128 MiB)
    char* ob = (char*)d_out;
    Wt    = (unsigned short*)ob;                    // 32 MiB
    xbuf  = (unsigned short*)(ob + 33554432);       //  8 MiB
    mixp  = (float*)(ob + 41943040);                // 64 KiB
    bmixp = mixp + 16384;                           // 64 KiB
    supb  = (unsigned short*)d_ws;                  // 128 MiB
  } else {
    char* ws = (char*)d_ws;
    Wt    = (unsigned short*)ws;                    // 32 MiB
    xbuf  = (unsigned short*)(ws + 33554432);       //  8 MiB
    mixp  = (float*)(ws + 33554432 + 8388608);      // 64 KiB
    bmixp = mixp + 16384;                           // 64 KiB
  }

  hipLaunchKernelGGL(mix_kernel, dim3(4), dim3(256), 0, stream, amp, phase, bias, mixp, bmixp);
  hipLaunchKernelGGL(cast_x_kernel, dim3(4096), dim3(256), 0, stream, x, xbuf);
  hipLaunchKernelGGL(transpose_w_kernel, dim3(16, 16, 16), dim3(256), 0, stream, W, Wt);
  if (big) {
    hipLaunchKernelGGL((gemm_kernel<true>), dim3(1024), dim3(512), 0, stream,
                       xbuf, Wt, mixp, bmixp, out, supb);
    hipLaunchKernelGGL(ln_bf16_kernel, dim3(65536), dim3(256), 0, stream,
                       supb, out, gamma, beta);
  } else {
    hipLaunchKernelGGL((gemm_kernel<false>), dim3(1024), dim3(512), 0, stream,
                       xbuf, Wt, mixp, bmixp, out, nullptr);
    hipLaunchKernelGGL(ln_kernel, dim3(65536), dim3(256), 0, stream, out, gamma, beta);
  }
}

// Round 4
// 323.418 us; speedup vs baseline: 1.1756x; 1.1756x over previous
//
#include <hip/hip_runtime.h>

typedef __attribute__((ext_vector_type(8))) short short8;
typedef __attribute__((ext_vector_type(4))) float f32x4;
typedef __attribute__((ext_vector_type(4))) unsigned short u16x4;

#define GLOAD16(g, l)                                                          \
  __builtin_amdgcn_global_load_lds(                                            \
      (const __attribute__((address_space(1))) unsigned int*)(g),              \
      (__attribute__((address_space(3))) unsigned int*)(l), 16, 0, 0)

__device__ __forceinline__ unsigned short f2bf(float f) {
  unsigned int u = __float_as_uint(f);
  u += 0x7FFFu + ((u >> 16) & 1u);   // RNE
  return (unsigned short)(u >> 16);
}
__device__ __forceinline__ float bf2f(unsigned short h) {
  return __uint_as_float(((unsigned int)h) << 16);
}

// ---------------------------------------------------------------- mix / bmix
__global__ void mix_kernel(const float* __restrict__ amp,
                           const float* __restrict__ phase,
                           const float* __restrict__ bias,
                           float* __restrict__ mix, float* __restrict__ bmix) {
  int q = blockIdx.x * blockDim.x + threadIdx.x;  // 0..1023
  float a[16];
  float mx = -1e30f;
  for (int s = 0; s < 16; ++s) {
    a[s] = amp[s * 1024 + q];
    mx = fmaxf(mx, a[s]);
  }
  float sum = 0.f;
  for (int s = 0; s < 16; ++s) {
    a[s] = __expf(a[s] - mx);
    sum += a[s];
  }
  float inv = 1.f / sum;
  for (int s = 0; s < 16; ++s) {
    float m = a[s] * inv * cosf(phase[s * 1024 + q]);
    mix[s * 1024 + q] = m;
    bmix[s * 1024 + q] = bias[s * 1024 + q] * m;
  }
}

// ---------------------------------------------------------------- cast x->bf16
__global__ void cast_x_kernel(const float* __restrict__ x,
                              unsigned short* __restrict__ xb) {
  int i = (blockIdx.x * blockDim.x + threadIdx.x) * 4;
  float4 v = *(const float4*)(x + i);
  union { unsigned short h[4]; uint2 u; } o;
  o.h[0] = f2bf(v.x); o.h[1] = f2bf(v.y); o.h[2] = f2bf(v.z); o.h[3] = f2bf(v.w);
  *(uint2*)(xb + i) = o.u;
}

// ------------------------------------------------- transpose+cast W -> Wt bf16
__global__ __launch_bounds__(256) void transpose_w_kernel(
    const float* __restrict__ W, unsigned short* __restrict__ Wt) {
  __shared__ unsigned short tile[64][66];
  const int s = blockIdx.z;
  const int q0 = blockIdx.x * 64, i0 = blockIdx.y * 64;
  const int t = threadIdx.x;
  const float* Ws = W + (size_t)s * 1048576;
  unsigned short* Wts = Wt + (size_t)s * 1048576;
  const int rq = t & 63, ri = t >> 6;
  #pragma unroll
  for (int p = 0; p < 16; ++p)
    tile[p * 4 + ri][rq] = f2bf(Ws[(size_t)(i0 + p * 4 + ri) * 1024 + q0 + rq]);
  __syncthreads();
  const int wq = t >> 3, wi = (t & 7) * 8;
  #pragma unroll
  for (int o = 0; o < 2; ++o) {
    union { unsigned short h[8]; short8 v; } u;
    #pragma unroll
    for (int e = 0; e < 8; ++e) u.h[e] = tile[wi + e][o * 32 + wq];
    *(short8*)(Wts + (size_t)(q0 + o * 32 + wq) * 1024 + i0 + wi) = u.v;
  }
}

// ---------------------------------------------------------------- bf16 GEMM
// 256x256 tile, BK=64, 8 waves (2Mx4N), 8-phase schedule (T2+T3+T4+T5).
// LDS: A/B each 4 planes [tile-parity(2)][half(2)] of 128rows x 64k (16KB).
// T2 swizzle (8-way): LDS(row, slot16) holds global slot16 ^ (row&7);
// applied as inverse-swizzled GLOBAL source (LDS dst linear, rule #21)
// and swizzled ds_read offsets c0 = ((lane>>4)^(row&7))*8, c1 = c0^32.
// Stage schedule unchanged from R3 (audited: every stage >=1 barrier after
// its slot's last read; vmcnt(4) at P4/P8 covers every read's data).
template <bool BF16SUP>
__global__ __launch_bounds__(512, 2) void gemm_kernel(
    const unsigned short* __restrict__ xb, const unsigned short* __restrict__ wt,
    const float* __restrict__ mix, const float* __restrict__ bmix,
    float* __restrict__ outf, unsigned short* __restrict__ sup) {
  __shared__ __align__(16) unsigned short As[4 * 8192];
  __shared__ __align__(16) unsigned short Bs[4 * 8192];

  const int tid = threadIdx.x;
  const int lane = tid & 63;
  const int wv = tid >> 6;
  const int wm = wv >> 2, wn = wv & 3;   // 2x4 waves, wave tile 128x64
  const int lr = lane & 15;
  const int c0 = (((lane >> 4) ^ (lr & 7)) * 8);   // swizzled k-chunk 0
  // chunk 1 offset = c0 ^ 32

  // XCD swizzle + L2 grouping
  const int id = blockIdx.x;
  const int swz = (id & 7) * 128 + (id >> 3);
  const int local = swz & 127;
  const int by = local & 15;
  const int bx = (swz >> 7) * 8 + (local >> 4);
  const int m0 = by * 256, n0 = bx * 256;

  // staging: thread covers LDS row tid>>3 (+64 for 2nd load), slot tid&7;
  // global k pre-swizzled so LDS write stays linear
  const int srow = tid >> 3;
  const int k8s = (((tid & 7) ^ (srow & 7)) * 8);
  const int t8 = tid * 8;
  const unsigned short* gA = xb + (size_t)(m0 + srow) * 1024 + k8s;
  const unsigned short* gB = wt + (size_t)(n0 + srow) * 1024 + k8s;

#define STG(gbase, lds, tile, half) do {                                       \
    const unsigned short* _g = (gbase) + (half) * 131072 + (tile) * 64;        \
    unsigned short* _l = (lds) + ((((tile) & 1) * 2 + (half)) * 8192) + t8;    \
    GLOAD16(_g, _l);                                                           \
    GLOAD16(_g + 65536, _l + 4096);                                            \
  } while (0)

  short8 a[4][2], bl[2][2], bh[2][2];
  f32x4 acc[8][4];
  #pragma unroll
  for (int i = 0; i < 8; ++i)
    #pragma unroll
    for (int j = 0; j < 4; ++j) acc[i][j] = (f32x4){0.f, 0.f, 0.f, 0.f};

#define RD_A(bank, hib) do {                                                   \
    const unsigned short* _p = &As[((bank) * 2 + wm) * 8192] +                 \
                               ((hib) * 64 + lr) * 64;                         \
    _Pragma("unroll")                                                          \
    for (int mi = 0; mi < 4; ++mi) {                                           \
      a[mi][0] = *(const short8*)(_p + mi * 1024 + c0);                        \
      a[mi][1] = *(const short8*)(_p + mi * 1024 + (c0 ^ 32));                 \
    }                                                                          \
  } while (0)

#define RD_B(dst, bank, hib) do {                                              \
    const unsigned short* _p = &Bs[((bank) * 2 + (wn >> 1)) * 8192] +          \
                               ((wn & 1) * 64 + (hib) * 32 + lr) * 64;         \
    _Pragma("unroll")                                                          \
    for (int ni = 0; ni < 2; ++ni) {                                           \
      dst[ni][0] = *(const short8*)(_p + ni * 1024 + c0);                      \
      dst[ni][1] = *(const short8*)(_p + ni * 1024 + (c0 ^ 32));               \
    }                                                                          \
  } while (0)

#define MMQ(M0, N0, BB)                                                        \
    _Pragma("unroll")                                                          \
    for (int mi = 0; mi < 4; ++mi)                                             \
      _Pragma("unroll")                                                        \
      for (int ni = 0; ni < 2; ++ni) {                                         \
        acc[(M0) + mi][(N0) + ni] = __builtin_amdgcn_mfma_f32_16x16x32_bf16(   \
            a[mi][0], BB[ni][0], acc[(M0) + mi][(N0) + ni], 0, 0, 0);          \
        acc[(M0) + mi][(N0) + ni] = __builtin_amdgcn_mfma_f32_16x16x32_bf16(   \
            a[mi][1], BB[ni][1], acc[(M0) + mi][(N0) + ni], 0, 0, 0);          \
      }

#define PH_SYNC()                                                              \
    __builtin_amdgcn_s_barrier();                                              \
    asm volatile("s_waitcnt lgkmcnt(0)" ::: "memory");                         \
    __builtin_amdgcn_sched_barrier(0);                                         \
    __builtin_amdgcn_s_setprio(1)

#define PH_END()                                                               \
    __builtin_amdgcn_s_setprio(0);                                             \
    __builtin_amdgcn_s_barrier()

  // prologue: tile0 all 4 halves + B_h0(1) + A_h0(1); keep last 2 in flight
  STG(gB, Bs, 0, 0); STG(gB, Bs, 0, 1);
  STG(gA, As, 0, 0); STG(gA, As, 0, 1);
  STG(gB, Bs, 1, 0); STG(gA, As, 1, 0);
  asm volatile("s_waitcnt vmcnt(4)" ::: "memory");
  __builtin_amdgcn_s_barrier();

  for (int j = 0; j < 8; ++j) {
    const int t1 = 2 * j + 1;
    // P1: Q00(t0)
    RD_A(0, 0); RD_B(bl, 0, 0);
    STG(gA, As, t1, 1);
    PH_SYNC(); MMQ(0, 0, bl); PH_END();
    // P2: Q01(t0)
    RD_B(bh, 0, 1);
    STG(gB, Bs, t1, 1);
    PH_SYNC(); MMQ(0, 2, bh); PH_END();
    // P3: Q11(t0)
    RD_A(0, 1);
    if (j < 7) STG(gB, Bs, t1 + 1, 0);
    PH_SYNC(); MMQ(4, 2, bh); PH_END();
    // P4: Q10(t0)
    if (j < 7) {
      STG(gB, Bs, t1 + 1, 1);
      asm volatile("s_waitcnt vmcnt(4)" ::: "memory");
    } else {
      asm volatile("s_waitcnt vmcnt(0)" ::: "memory");
    }
    PH_SYNC(); MMQ(4, 0, bl); PH_END();
    // P5: Q00(t1)
    RD_A(1, 0); RD_B(bl, 1, 0);
    if (j < 7) STG(gA, As, t1 + 1, 0);
    PH_SYNC(); MMQ(0, 0, bl); PH_END();
    // P6: Q01(t1)
    RD_B(bh, 1, 1);
    if (j < 7) STG(gA, As, t1 + 1, 1);
    PH_SYNC(); MMQ(0, 2, bh); PH_END();
    // P7: Q11(t1)
    RD_A(1, 1);
    if (j < 7) STG(gB, Bs, t1 + 2, 0);
    PH_SYNC(); MMQ(4, 2, bh); PH_END();
    // P8: Q10(t1)
    if (j < 7) {
      STG(gA, As, t1 + 2, 0);
      asm volatile("s_waitcnt vmcnt(4)" ::: "memory");
    }
    PH_SYNC(); MMQ(4, 0, bl); PH_END();
  }
#undef STG
#undef RD_A
#undef RD_B
#undef MMQ
#undef PH_SYNC
#undef PH_END

  // epilogue: sup = acc*mix + bmix
  #pragma unroll
  for (int ni = 0; ni < 4; ++ni) {
    const int n = n0 + wn * 64 + ni * 16 + lr;
    const float mv = mix[n];
    const float bvv = bmix[n];
    #pragma unroll
    for (int mi = 0; mi < 8; ++mi) {
      const int m = m0 + wm * 128 + mi * 16 + (lane >> 4) * 4;
      #pragma unroll
      for (int r = 0; r < 4; ++r) {
        float v = acc[mi][ni][r] * mv + bvv;
        if (BF16SUP)
          sup[(size_t)(m + r) * 16384 + n] = f2bf(v);
        else
          outf[(size_t)(m + r) * 16384 + n] = v;
      }
    }
  }
}

// ------------------------------------------------------- LN from bf16 sup
__global__ __launch_bounds__(256) void ln_bf16_kernel(
    const unsigned short* __restrict__ sup, float* __restrict__ out,
    const float* __restrict__ gamma, const float* __restrict__ beta) {
  __shared__ float red[8];
  const int t = threadIdx.x;
  const size_t base = (size_t)blockIdx.x * 1024;
  u16x4 raw = *(const u16x4*)(sup + base + t * 4);
  float v[4];
  #pragma unroll
  for (int j = 0; j < 4; ++j) v[j] = bf2f(raw[j]);
  float s = v[0] + v[1] + v[2] + v[3];
  float ss = v[0] * v[0] + v[1] * v[1] + v[2] * v[2] + v[3] * v[3];
  #pragma unroll
  for (int m = 32; m >= 1; m >>= 1) {
    s += __shfl_xor(s, m);
    ss += __shfl_xor(ss, m);
  }
  const int wv = t >> 6;
  if ((t & 63) == 0) { red[wv * 2] = s; red[wv * 2 + 1] = ss; }
  __syncthreads();
  const float S = red[0] + red[2] + red[4] + red[6];
  const float SS = red[1] + red[3] + red[5] + red[7];
  const float mean = S * (1.0f / 1024.0f);
  const float var = SS * (1.0f / 1024.0f) - mean * mean;
  const float rstd = rsqrtf(var + 1e-5f);
  const float4 g = *(const float4*)(gamma + t * 4);
  const float4 b = *(const float4*)(beta + t * 4);
  float4 o;
  o.x = (v[0] - mean) * rstd * g.x + b.x;
  o.y = (v[1] - mean) * rstd * g.y + b.y;
  o.z = (v[2] - mean) * rstd * g.z + b.z;
  o.w = (v[3] - mean) * rstd * g.w + b.w;
  *(float4*)(out + base + t * 4) = o;
}

// ------------------------------------------------------- in-place f32 LN
__global__ __launch_bounds__(256) void ln_kernel(float* __restrict__ out,
                                                 const float* __restrict__ gamma,
                                                 const float* __restrict__ beta) {
  __shared__ float red[8];
  const int t = threadIdx.x;
  const size_t base = (size_t)blockIdx.x * 1024;
  float4 v = *(const float4*)(out + base + t * 4);
  float s = v.x + v.y + v.z + v.w;
  float ss = v.x * v.x + v.y * v.y + v.z * v.z + v.w * v.w;
  #pragma unroll
  for (int m = 32; m >= 1; m >>= 1) {
    s += __shfl_xor(s, m);
    ss += __shfl_xor(ss, m);
  }
  const int wv = t >> 6;
  if ((t & 63) == 0) { red[wv * 2] = s; red[wv * 2 + 1] = ss; }
  __syncthreads();
  const float S = red[0] + red[2] + red[4] + red[6];
  const float SS = red[1] + red[3] + red[5] + red[7];
  const float mean = S * (1.0f / 1024.0f);
  const float var = SS * (1.0f / 1024.0f) - mean * mean;
  const float rstd = rsqrtf(var + 1e-5f);
  const float4 g = *(const float4*)(gamma + t * 4);
  const float4 b = *(const float4*)(beta + t * 4);
  float4 o;
  o.x = (v.x - mean) * rstd * g.x + b.x;
  o.y = (v.y - mean) * rstd * g.y + b.y;
  o.z = (v.z - mean) * rstd * g.z + b.z;
  o.w = (v.w - mean) * rstd * g.w + b.w;
  *(float4*)(out + base + t * 4) = o;
}

extern "C" void kernel_launch(void* const* d_in, const int* in_sizes, int n_in,
                              void* d_out, int out_size, void* d_ws, size_t ws_size,
                              hipStream_t stream) {
  (void)in_sizes; (void)n_in; (void)out_size;
  const float* x     = (const float*)d_in[0];  // [4096,1024]
  const float* W     = (const float*)d_in[1];  // [16,1024,1024]
  const float* bias  = (const float*)d_in[2];  // [16,1024]
  const float* amp   = (const float*)d_in[3];  // [16,1024]
  const float* phase = (const float*)d_in[4];  // [16,1024]
  const float* gamma = (const float*)d_in[5];  // [1024]
  const float* beta  = (const float*)d_in[6];  // [1024]
  float* out = (float*)d_out;                  // [4096,16,1024] = 256 MiB

  const bool big = ws_size >= (size_t)134217728ULL;  // bf16 sup fits in ws

  unsigned short *Wt, *xbuf, *supb = nullptr;
  float *mixp, *bmixp;
  if (big) {
    // scratch Wt/xb/mix live in d_out (fully rewritten by LN afterwards);
    // ws holds bf16 sup (exactly 128 MiB)
    char* ob = (char*)d_out;
    Wt    = (unsigned short*)ob;                    // 32 MiB
    xbuf  = (unsigned short*)(ob + 33554432);       //  8 MiB
    mixp  = (float*)(ob + 41943040);                // 64 KiB
    bmixp = mixp + 16384;                           // 64 KiB
    supb  = (unsigned short*)d_ws;                  // 128 MiB
  } else {
    char* ws = (char*)d_ws;
    Wt    = (unsigned short*)ws;                    // 32 MiB
    xbuf  = (unsigned short*)(ws + 33554432);       //  8 MiB
    mixp  = (float*)(ws + 33554432 + 8388608);      // 64 KiB
    bmixp = mixp + 16384;                           // 64 KiB
  }

  hipLaunchKernelGGL(mix_kernel, dim3(4), dim3(256), 0, stream, amp, phase, bias, mixp, bmixp);
  hipLaunchKernelGGL(cast_x_kernel, dim3(4096), dim3(256), 0, stream, x, xbuf);
  hipLaunchKernelGGL(transpose_w_kernel, dim3(16, 16, 16), dim3(256), 0, stream, W, Wt);
  if (big) {
    hipLaunchKernelGGL((gemm_kernel<true>), dim3(1024), dim3(512), 0, stream,
                       xbuf, Wt, mixp, bmixp, out, supb);
    hipLaunchKernelGGL(ln_bf16_kernel, dim3(65536), dim3(256), 0, stream,
                       supb, out, gamma, beta);
  } else {
    hipLaunchKernelGGL((gemm_kernel<false>), dim3(1024), dim3(512), 0, stream,
                       xbuf, Wt, mixp, bmixp, out, nullptr);
    hipLaunchKernelGGL(ln_kernel, dim3(65536), dim3(256), 0, stream, out, gamma, beta);
  }
}